// Round 1
// 119.908 us; speedup vs baseline: 1.0039x; 1.0039x over previous
//
#include <hip/hip_runtime.h>
#include <math.h>

// Problem constants (fixed by setup_inputs)
#define Nn 32
#define Cc 128
#define Ss 4096
#define Kk 64
#define NCHUNK 16
#define SCHUNK (Ss / NCHUNK)   // 256 pixels per block
#define ST 64                  // pixels per subtile
#define NSUB (SCHUNK / ST)     // 4 subtiles per block
#define BLK 256

// LDS strides (chosen for 16B-aligned fragment reads + even bank spread)
#define XCS 72    // xC [c][s] stride in ushorts (s-contig rows, 36 dw, 16B-aligned)
#define XTS 136   // xT [s][c] stride in ushorts (c-contig rows, 68 dw, 16B-aligned)
#define LKS 68    // Lbuf [s][k] stride in floats (aliases xT region: 68 dw == 136 u16)
#define AS  72    // aB [k][s] stride in ushorts
#define RS  17    // red stride in floats (odd -> conflict-free column reads)

typedef __attribute__((ext_vector_type(8))) short short8;   // bf16x8 MFMA frag
typedef __attribute__((ext_vector_type(4))) float float4v;  // fp32x4 MFMA acc

__device__ __forceinline__ unsigned f2bf(float f) {
    unsigned u = __builtin_bit_cast(unsigned, f);
    return (u + 0x7fffu + ((u >> 16) & 1u)) >> 16;   // RNE f32->bf16
}
__device__ __forceinline__ unsigned pack2(float a, float b) {
    return f2bf(a) | (f2bf(b) << 16);
}

// Fused: stage bf16 x (2 layouts) -> L2-norm -> MFMA logits -> softmax ->
// MFMA VLAD (persistent AGPR/VGPR acc) -> atomic commit.
// MFMA 16x16x32 bf16 layouts (HW-verified per guide):
//   A[m=lane&15][k=quad*8+j], B[k=quad*8+j][n=lane&15], D col=lane&15 row=4*quad+reg.
// T14 (round 1): register prefetch of next subtile's x — loads issued right
// after the current stage consumes pf[], completing under GEMM1/softmax/GEMM2.
__global__ __launch_bounds__(BLK, 2) void netvlad_main(
    const float* __restrict__ x,
    const float* __restrict__ conv_w,
    const float* __restrict__ conv_b,
    float* __restrict__ vlad,
    float* __restrict__ asum)
{
    __shared__ __align__(16) unsigned short xC[Cc * XCS];  // 18432 B raw-x bf16 [c][s]
    __shared__ __align__(16) float Lbuf[ST * LKS];         // 17408 B logits [s][k] / xT alias
    __shared__ __align__(16) unsigned short aB[Kk * AS];   // 9216 B  a' bf16 [k][s]
    __shared__ float red[ST * RS];                         // 4352 B  ssq partials
    __shared__ float invn[ST];
    unsigned short* xT = (unsigned short*)Lbuf;            // raw-x bf16 [s][c]

    const int t    = threadIdx.x;
    const int n    = blockIdx.y;
    const int w    = t >> 6;      // wave id: k-rows 16w..16w+15
    const int l    = t & 63;
    const int m    = l & 15;
    const int quad = l >> 4;
    const int p    = t >> 2;      // softmax pixel
    const int ii   = t & 3;       // softmax k-slice

    // ---- one-time: conv_w A-fragments (bf16, regs) + bias for D rows ----
    short8 wfrag[4];
    {
        const float* wr_ = conv_w + (16 * w + m) * Cc;
#pragma unroll
        for (int ks = 0; ks < 4; ++ks) {
            float4 wa = *(const float4*)(wr_ + 32 * ks + 8 * quad);
            float4 wb = *(const float4*)(wr_ + 32 * ks + 8 * quad + 4);
            union { short8 s8; unsigned u[4]; } W_;
            W_.u[0] = pack2(wa.x, wa.y);
            W_.u[1] = pack2(wa.z, wa.w);
            W_.u[2] = pack2(wb.x, wb.y);
            W_.u[3] = pack2(wb.z, wb.w);
            wfrag[ks] = W_.s8;
        }
    }
    float bias_r[4];
#pragma unroll
    for (int r = 0; r < 4; ++r) bias_r[r] = conv_b[16 * w + 4 * quad + r];

    float4v acc[8];               // VLAD acc: 16k x 128c per wave, persistent
#pragma unroll
    for (int nt = 0; nt < 8; ++nt) acc[nt] = (float4v){0.f, 0.f, 0.f, 0.f};
    float asum_part[16];
#pragma unroll
    for (int j = 0; j < 16; ++j) asum_part[j] = 0.f;

    const float* xn = x + (size_t)n * Cc * Ss;

    // ---- T14 prefetch: preload subtile 0 into registers ----
    const int sq   = (t & 15) << 2;
    const int crow = t >> 4;
    const float* xbase = xn + (size_t)crow * Ss + blockIdx.x * SCHUNK + sq;
    float4 pf[8];
#pragma unroll
    for (int r = 0; r < 8; ++r)
        pf[r] = *(const float4*)(xbase + (size_t)(16 * r) * Ss);

    for (int sub = 0; sub < NSUB; ++sub) {
        __syncthreads();  // prior GEMM2 reads of xC/aB done

        // ---- stage: consume prefetched fp32 -> ssq partials + bf16 xC [c][s] ----
        {
            float sp0 = 0.f, sp1 = 0.f, sp2 = 0.f, sp3 = 0.f;
#pragma unroll
            for (int r = 0; r < 8; ++r) {
                float4 v = pf[r];
                sp0 += v.x * v.x; sp1 += v.y * v.y;
                sp2 += v.z * v.z; sp3 += v.w * v.w;
                uint2 pk = make_uint2(pack2(v.x, v.y), pack2(v.z, v.w));
                *(uint2*)&xC[(crow + 16 * r) * XCS + sq] = pk;
            }
            red[(sq + 0) * RS + crow] = sp0;
            red[(sq + 1) * RS + crow] = sp1;
            red[(sq + 2) * RS + crow] = sp2;
            red[(sq + 3) * RS + crow] = sp3;
        }
        // ---- issue next subtile's loads NOW; they complete under GEMM1/softmax/GEMM2
        if (sub < NSUB - 1) {
#pragma unroll
            for (int r = 0; r < 8; ++r)
                pf[r] = *(const float4*)(xbase + (size_t)(16 * r) * Ss + (sub + 1) * ST);
        }
        __syncthreads();

        // ---- invn (t<64) ----
        if (t < ST) {
            float tot = 0.f;
#pragma unroll
            for (int i = 0; i < 16; ++i) tot += red[t * RS + i];
            invn[t] = 1.0f / fmaxf(sqrtf(tot), 1e-12f);
        }
        // ---- build xT [s][c] from xC (16B writes; lane-spread over s) ----
        {
            int s = t & 63, oct0 = t >> 6;
#pragma unroll
            for (int q = 0; q < 4; ++q) {
                int oct = oct0 + 4 * q;   // c-octet 0..15
                uint4 dd;
                dd.x = (unsigned)xC[(8 * oct + 0) * XCS + s] | ((unsigned)xC[(8 * oct + 1) * XCS + s] << 16);
                dd.y = (unsigned)xC[(8 * oct + 2) * XCS + s] | ((unsigned)xC[(8 * oct + 3) * XCS + s] << 16);
                dd.z = (unsigned)xC[(8 * oct + 4) * XCS + s] | ((unsigned)xC[(8 * oct + 5) * XCS + s] << 16);
                dd.w = (unsigned)xC[(8 * oct + 6) * XCS + s] | ((unsigned)xC[(8 * oct + 7) * XCS + s] << 16);
                *(uint4*)&xT[s * XTS + 8 * oct] = dd;
            }
        }
        __syncthreads();

        // ---- GEMM1 (MFMA): L[16w+ k][s] = W x rawX, wave does 4 s-tiles x 4 c-steps
        float4v Lr[4];
#pragma unroll
        for (int nt = 0; nt < 4; ++nt) Lr[nt] = (float4v){0.f, 0.f, 0.f, 0.f};
#pragma unroll
        for (int nt = 0; nt < 4; ++nt) {
#pragma unroll
            for (int ks = 0; ks < 4; ++ks) {
                short8 b = *(const short8*)&xT[(16 * nt + m) * XTS + 32 * ks + 8 * quad];
                Lr[nt] = __builtin_amdgcn_mfma_f32_16x16x32_bf16(wfrag[ks], b, Lr[nt], 0, 0, 0);
            }
        }
        __syncthreads();  // all xT reads done -> safe to overwrite with Lbuf

        // epilogue: *invn[s] + bias[k]; write [s][k] fp32
#pragma unroll
        for (int nt = 0; nt < 4; ++nt) {
            float iv = invn[16 * nt + m];
            float4 o;
            o.x = Lr[nt].x * iv + bias_r[0];
            o.y = Lr[nt].y * iv + bias_r[1];
            o.z = Lr[nt].z * iv + bias_r[2];
            o.w = Lr[nt].w * iv + bias_r[3];
            *(float4*)&Lbuf[(16 * nt + m) * LKS + 16 * w + 4 * quad] = o;
        }
        __syncthreads();

        // ---- softmax over k per pixel p (4-thread team via shfl) ----
        {
            float lv[16];
#pragma unroll
            for (int j = 0; j < 16; ++j) lv[j] = Lbuf[p * LKS + ii + 4 * j];
            float mx = lv[0];
#pragma unroll
            for (int j = 1; j < 16; ++j) mx = fmaxf(mx, lv[j]);
            mx = fmaxf(mx, __shfl_xor(mx, 1));
            mx = fmaxf(mx, __shfl_xor(mx, 2));
            float e[16];
            float lsum = 0.f;
#pragma unroll
            for (int j = 0; j < 16; ++j) { e[j] = __expf(lv[j] - mx); lsum += e[j]; }
            lsum += __shfl_xor(lsum, 1);
            lsum += __shfl_xor(lsum, 2);
            float itot = 1.0f / lsum;
            float sca  = itot * invn[p];   // fold invn into a' (x in GEMM2 is raw)
#pragma unroll
            for (int j = 0; j < 16; ++j) {
                float av = e[j] * itot;
                asum_part[j] += av;                               // raw a for centroid term
                aB[(ii + 4 * j) * AS + p] = (unsigned short)f2bf(e[j] * sca);
            }
        }
        __syncthreads();

        // ---- GEMM2 (MFMA): V[16w+k][c] += a'[k][s] x rawX^T[s][c] ----
#pragma unroll
        for (int ks = 0; ks < 2; ++ks) {
            short8 af = *(const short8*)&aB[(16 * w + m) * AS + 32 * ks + 8 * quad];
#pragma unroll
            for (int nt = 0; nt < 8; ++nt) {
                short8 bf_ = *(const short8*)&xC[(16 * nt + m) * XCS + 32 * ks + 8 * quad];
                acc[nt] = __builtin_amdgcn_mfma_f32_16x16x32_bf16(af, bf_, acc[nt], 0, 0, 0);
            }
        }
    }

    // ---- commit vlad partials: lane holds D[k=16w+4quad+r][c=16nt+m] ----
    float* vb = vlad + ((size_t)n * Kk + 16 * w + 4 * quad) * Cc + m;
#pragma unroll
    for (int nt = 0; nt < 8; ++nt) {
        atomicAdd(vb + 0 * Cc + 16 * nt, acc[nt].x);
        atomicAdd(vb + 1 * Cc + 16 * nt, acc[nt].y);
        atomicAdd(vb + 2 * Cc + 16 * nt, acc[nt].z);
        atomicAdd(vb + 3 * Cc + 16 * nt, acc[nt].w);
    }

    // ---- block-reduce asum then one atomic per k (reuse Lbuf) ----
    __syncthreads();
#pragma unroll
    for (int j = 0; j < 16; ++j) Lbuf[p * LKS + ii + 4 * j] = asum_part[j];
    __syncthreads();
    if (t < Kk) {
        float s_ = 0.f;
        for (int p2 = 0; p2 < ST; ++p2) s_ += Lbuf[p2 * LKS + t];
        atomicAdd(&asum[n * Kk + t], s_);
    }
}

// Parallel finalize: one block per n. Phase 1: per-k intra-norm scale via
// 4-thread teams + LDS reduce. Phase 2 (round 1: 8x more MLP): 256 threads =
// 32 c-quads x 8 k-slices, float4 loads, LDS tree combine.
__global__ __launch_bounds__(256) void netvlad_final(
    const float* __restrict__ vlad, const float* __restrict__ asum,
    const float* __restrict__ centroids, const float* __restrict__ fc_w,
    float* __restrict__ out)
{
    __shared__ float scale_s[Kk];
    __shared__ float asum_s[Kk];
    __shared__ float red2[Kk][4];
    __shared__ float4 osum[8][32];

    const int n = blockIdx.x;
    const int t = threadIdx.x;
    const int k = t >> 2;
    const int q = t & 3;

    const float* vr = vlad + ((size_t)n * Kk + k) * Cc + q * 32;
    const float* cr = centroids + k * Cc + q * 32;
    const float  as = asum[n * Kk + k];

    float ssq = 0.f;
#pragma unroll
    for (int i = 0; i < 8; ++i) {
        float4 v4 = *(const float4*)(vr + 4 * i);
        float4 c4 = *(const float4*)(cr + 4 * i);
        float d0 = v4.x - as * c4.x;
        float d1 = v4.y - as * c4.y;
        float d2 = v4.z - as * c4.z;
        float d3 = v4.w - as * c4.w;
        ssq += d0 * d0 + d1 * d1 + d2 * d2 + d3 * d3;
    }
    red2[k][q] = ssq;
    __syncthreads();
    if (q == 0) {
        float tot = red2[k][0] + red2[k][1] + red2[k][2] + red2[k][3];
        scale_s[k] = fc_w[k] / fmaxf(sqrtf(tot), 1e-12f);
        asum_s[k]  = as;
    }
    __syncthreads();

    // phase 2: thread t = (sl = t>>5 in 0..7, cq = t&31); each sums 8 k's
    {
        const int cq = t & 31;
        const int sl = t >> 5;
        const float* vb2 = vlad + (size_t)n * Kk * Cc + 4 * cq;
        const float* cb2 = centroids + 4 * cq;
        float ox = 0.f, oy = 0.f, oz = 0.f, ow = 0.f;
#pragma unroll
        for (int j = 0; j < 8; ++j) {
            const int k2 = 8 * j + sl;
            float4 v4 = *(const float4*)(vb2 + (size_t)k2 * Cc);
            float4 c4 = *(const float4*)(cb2 + (size_t)k2 * Cc);
            float sc = scale_s[k2];
            float a2 = asum_s[k2];
            ox += sc * (v4.x - a2 * c4.x);
            oy += sc * (v4.y - a2 * c4.y);
            oz += sc * (v4.z - a2 * c4.z);
            ow += sc * (v4.w - a2 * c4.w);
        }
        osum[sl][cq] = make_float4(ox, oy, oz, ow);
    }
    __syncthreads();
    if (t < 32) {
        float4 tot = osum[0][t];
#pragma unroll
        for (int s2 = 1; s2 < 8; ++s2) {
            float4 o2 = osum[s2][t];
            tot.x += o2.x; tot.y += o2.y; tot.z += o2.z; tot.w += o2.w;
        }
        *(float4*)&out[n * Cc + 4 * t] = tot;
    }
}

extern "C" void kernel_launch(void* const* d_in, const int* in_sizes, int n_in,
                              void* d_out, int out_size, void* d_ws, size_t ws_size,
                              hipStream_t stream) {
    (void)in_sizes; (void)n_in; (void)out_size; (void)ws_size;
    const float* x         = (const float*)d_in[0];
    const float* conv_w    = (const float*)d_in[1];
    const float* conv_b    = (const float*)d_in[2];
    const float* centroids = (const float*)d_in[3];
    const float* fc_w      = (const float*)d_in[4];
    float* out = (float*)d_out;

    float* vlad = (float*)d_ws;                         // [N][K][C] = 1 MB
    float* asum = vlad + (size_t)Nn * Kk * Cc;          // [N][K]    = 8 KB
    size_t zero_bytes = ((size_t)Nn * Kk * Cc + (size_t)Nn * Kk) * sizeof(float);
    hipMemsetAsync(d_ws, 0, zero_bytes, stream);        // ws is poisoned 0xAA each call

    dim3 grid(NCHUNK, Nn);
    netvlad_main<<<grid, BLK, 0, stream>>>(x, conv_w, conv_b, vlad, asum);
    netvlad_final<<<Nn, 256, 0, stream>>>(vlad, asum, centroids, fc_w, out);
}